// Round 2
// baseline (188.016 us; speedup 1.0000x reference)
//
#include <hip/hip_runtime.h>

#define N_Q 4096
#define M_T 16384
#define D_ 32
#define OUT_ 16
#define EPS_ 1e-6f
#define MBT 128   // points per LDS tile in phase 1

// ---------------------------------------------------------------------------
// Phase 0: xqs = x / exp(w), xts = train_x / exp(w), plus row norms.
// One wave handles 8 rows: lane l -> row base+(l>>3), d0=(l&7)*4 (coalesced 1KB/wave).
// ---------------------------------------------------------------------------
__global__ __launch_bounds__(256) void p0_scale(const float* __restrict__ x,
                                                const float* __restrict__ tx,
                                                const float* __restrict__ wts,
                                                float* __restrict__ xqs,
                                                float* __restrict__ xts,
                                                float* __restrict__ xqn,
                                                float* __restrict__ xtn) {
  int wid  = (blockIdx.x * blockDim.x + threadIdx.x) >> 6;
  int lane = threadIdx.x & 63;
  int row  = wid * 8 + (lane >> 3);
  int d0   = (lane & 7) * 4;
  if (row >= N_Q + M_T) return;
  const float* src; float* dst; float* ndst; int ri;
  if (row < N_Q) { src = x;  dst = xqs; ndst = xqn; ri = row; }
  else           { src = tx; dst = xts; ndst = xtn; ri = row - N_Q; }
  float4 v = *(const float4*)(src + (size_t)ri * D_ + d0);
  // exact reference arithmetic: divide by exp(w)
  float s0 = expf(wts[d0 + 0]);
  float s1 = expf(wts[d0 + 1]);
  float s2 = expf(wts[d0 + 2]);
  float s3 = expf(wts[d0 + 3]);
  v.x /= s0; v.y /= s1; v.z /= s2; v.w /= s3;
  *(float4*)(dst + (size_t)ri * D_ + d0) = v;
  float nrm = v.x * v.x + v.y * v.y + v.z * v.z + v.w * v.w;
  nrm += __shfl_xor(nrm, 1);
  nrm += __shfl_xor(nrm, 2);
  nrm += __shfl_xor(nrm, 4);
  if ((lane & 7) == 0) ndst[ri] = nrm;
}

// ---------------------------------------------------------------------------
// Sorted-ascending top-5 insert, all register indices compile-time constant.
// Caller guarantees v < s[4].
// ---------------------------------------------------------------------------
__device__ __forceinline__ void insert5(float (&s)[5], int (&id)[5], float v, int vi) {
  float cs = v; int ci = vi;
#pragma unroll
  for (int k = 0; k < 5; ++k) {
    bool lt   = cs < s[k];
    float ts  = s[k]; int ti = id[k];
    s[k]  = lt ? cs : ts;
    id[k] = lt ? ci : ti;
    cs    = lt ? ts : cs;
    ci    = lt ? ti : ci;
  }
}

// ---------------------------------------------------------------------------
// Phase 1: per (query-group, M-chunk) block, per-thread 4 resident queries,
// stream 128-point tiles through LDS with broadcast ds_read_b128.
// Writes per-query per-chunk top-5 (sq, idx) partials to workspace.
// ---------------------------------------------------------------------------
__global__ __launch_bounds__(256, 2) void p1_topk(const float* __restrict__ xqs,
                                                  const float* __restrict__ xqn,
                                                  const float* __restrict__ xts,
                                                  const float* __restrict__ xtn,
                                                  float* __restrict__ psq,
                                                  int* __restrict__ pidx,
                                                  int NC, int MB) {
  __shared__ float sxt[MBT * D_];
  __shared__ float sxtn[MBT];
  const int chunk = blockIdx.x;
  const int t     = threadIdx.x;
  const int q0    = blockIdx.y * 1024 + t * 4;

  float xq[4][32];
  float qn[4];
#pragma unroll
  for (int q = 0; q < 4; ++q) {
#pragma unroll
    for (int c = 0; c < 8; ++c) {
      float4 v = *(const float4*)(xqs + (size_t)(q0 + q) * D_ + c * 4);
      xq[q][c * 4 + 0] = v.x; xq[q][c * 4 + 1] = v.y;
      xq[q][c * 4 + 2] = v.z; xq[q][c * 4 + 3] = v.w;
    }
    qn[q] = xqn[q0 + q];
  }

  float s[4][5]; int id[4][5];
#pragma unroll
  for (int q = 0; q < 4; ++q)
#pragma unroll
    for (int k = 0; k < 5; ++k) { s[q][k] = 3.0e38f; id[q][k] = 0; }

  const int jbase = chunk * MB;
  for (int tile = 0; tile < MB; tile += MBT) {
    __syncthreads();
    // stage 128 points x 32 floats = 1024 float4, linear, coalesced
#pragma unroll
    for (int c = 0; c < 4; ++c) {
      ((float4*)sxt)[t + c * 256] =
          ((const float4*)(xts + (size_t)(jbase + tile) * D_))[t + c * 256];
    }
    if (t < MBT) sxtn[t] = xtn[jbase + tile + t];
    __syncthreads();

    for (int j = 0; j < MBT; ++j) {
      const float* p = sxt + j * D_;
      float d0 = 0.f, d1 = 0.f, d2 = 0.f, d3 = 0.f;
#pragma unroll
      for (int c = 0; c < 8; ++c) {
        float4 v = *(const float4*)(p + c * 4);   // wave-uniform -> LDS broadcast
        d0 = fmaf(xq[0][c * 4 + 0], v.x, d0);
        d0 = fmaf(xq[0][c * 4 + 1], v.y, d0);
        d0 = fmaf(xq[0][c * 4 + 2], v.z, d0);
        d0 = fmaf(xq[0][c * 4 + 3], v.w, d0);
        d1 = fmaf(xq[1][c * 4 + 0], v.x, d1);
        d1 = fmaf(xq[1][c * 4 + 1], v.y, d1);
        d1 = fmaf(xq[1][c * 4 + 2], v.z, d1);
        d1 = fmaf(xq[1][c * 4 + 3], v.w, d1);
        d2 = fmaf(xq[2][c * 4 + 0], v.x, d2);
        d2 = fmaf(xq[2][c * 4 + 1], v.y, d2);
        d2 = fmaf(xq[2][c * 4 + 2], v.z, d2);
        d2 = fmaf(xq[2][c * 4 + 3], v.w, d2);
        d3 = fmaf(xq[3][c * 4 + 0], v.x, d3);
        d3 = fmaf(xq[3][c * 4 + 1], v.y, d3);
        d3 = fmaf(xq[3][c * 4 + 2], v.z, d3);
        d3 = fmaf(xq[3][c * 4 + 3], v.w, d3);
      }
      const float tn = sxtn[j];
      const int   gj = jbase + tile + j;
      float sq0 = qn[0] + tn - 2.0f * d0;
      if (sq0 < s[0][4]) insert5(s[0], id[0], sq0, gj);
      float sq1 = qn[1] + tn - 2.0f * d1;
      if (sq1 < s[1][4]) insert5(s[1], id[1], sq1, gj);
      float sq2 = qn[2] + tn - 2.0f * d2;
      if (sq2 < s[2][4]) insert5(s[2], id[2], sq2, gj);
      float sq3 = qn[3] + tn - 2.0f * d3;
      if (sq3 < s[3][4]) insert5(s[3], id[3], sq3, gj);
    }
  }

  const int nc5 = NC * 5;
#pragma unroll
  for (int q = 0; q < 4; ++q)
#pragma unroll
    for (int k = 0; k < 5; ++k) {
      psq [(size_t)(q0 + q) * nc5 + chunk * 5 + k] = s[q][k];
      pidx[(size_t)(q0 + q) * nc5 + chunk * 5 + k] = id[q][k];
    }
}

// ---------------------------------------------------------------------------
// Phase 2: one wave per query; lane-strided scan of NC*5 partials, shfl_xor
// butterfly merge, then weighted gather of train_y.
// ---------------------------------------------------------------------------
__global__ __launch_bounds__(256) void p2_merge(const float* __restrict__ psq,
                                                const int* __restrict__ pidx,
                                                const float* __restrict__ ty,
                                                float* __restrict__ out,
                                                int NC) {
  const int q    = (blockIdx.x * blockDim.x + threadIdx.x) >> 6;
  const int lane = threadIdx.x & 63;
  if (q >= N_Q) return;
  const int nc5 = NC * 5;

  float s[5]; int id[5];
#pragma unroll
  for (int k = 0; k < 5; ++k) { s[k] = 3.0e38f; id[k] = 0; }

  for (int c = lane; c < nc5; c += 64) {
    float v = psq[(size_t)q * nc5 + c];
    if (v < s[4]) insert5(s, id, v, pidx[(size_t)q * nc5 + c]);
  }

  // butterfly merge: shuffles unconditional, inserts guarded
#pragma unroll
  for (int step = 1; step < 64; step <<= 1) {
    float ov[5]; int oi[5];
#pragma unroll
    for (int k = 0; k < 5; ++k) {
      ov[k] = __shfl_xor(s[k], step);
      oi[k] = __shfl_xor(id[k], step);
    }
#pragma unroll
    for (int k = 0; k < 5; ++k) {
      if (ov[k] < s[4]) insert5(s, id, ov[k], oi[k]);
    }
  }

  // all lanes now hold the identical global top-5 (ascending sq)
  float dinv[5]; float wsum = 0.f;
#pragma unroll
  for (int k = 0; k < 5; ++k) {
    dinv[k] = 1.0f / sqrtf(fmaxf(s[k], 0.f) + EPS_);
    wsum += dinv[k];
  }
  if (lane < OUT_) {
    float acc = 0.f;
#pragma unroll
    for (int k = 0; k < 5; ++k)
      acc = fmaf(dinv[k] / wsum, ty[(size_t)id[k] * OUT_ + lane], acc);
    out[(size_t)q * OUT_ + lane] = acc;
  }
}

// ---------------------------------------------------------------------------
extern "C" void kernel_launch(void* const* d_in, const int* in_sizes, int n_in,
                              void* d_out, int out_size, void* d_ws, size_t ws_size,
                              hipStream_t stream) {
  const float* x   = (const float*)d_in[0];
  const float* tx  = (const float*)d_in[1];
  const float* ty  = (const float*)d_in[2];
  const float* wts = (const float*)d_in[3];
  float* out = (float*)d_out;

  char* ws = (char*)d_ws;
  size_t off = 0;
  float* xqs = (float*)(ws + off); off += (size_t)N_Q * D_ * 4;
  float* xts = (float*)(ws + off); off += (size_t)M_T * D_ * 4;
  float* xqn = (float*)(ws + off); off += (size_t)N_Q * 4;
  float* xtn = (float*)(ws + off); off += (size_t)M_T * 4;

  // pick the largest chunk count whose partial lists fit in the workspace
  int NC = 128;
  while (NC > 8) {
    size_t need = off + (size_t)N_Q * NC * 5 * 8;
    if (need <= ws_size) break;
    NC >>= 1;
  }
  const int MB = M_T / NC;
  float* psq  = (float*)(ws + off); off += (size_t)N_Q * NC * 5 * 4;
  int*   pidx = (int*)(ws + off);

  p0_scale<<<dim3((N_Q + M_T) / 32), dim3(256), 0, stream>>>(x, tx, wts, xqs, xts, xqn, xtn);
  p1_topk<<<dim3(NC, 4), dim3(256), 0, stream>>>(xqs, xqn, xts, xtn, psq, pidx, NC, MB);
  p2_merge<<<dim3(N_Q * 64 / 256), dim3(256), 0, stream>>>(psq, pidx, ty, out, NC);
}

// Round 4
// 184.918 us; speedup vs baseline: 1.0167x; 1.0167x over previous
//
#include <hip/hip_runtime.h>

#define N_Q 4096
#define M_T 16384
#define D_ 32
#define OUT_ 16
#define EPS_ 1e-6f
#define MBT 128   // points per LDS tile in phase 1
#define QPT 2     // queries per thread in phase 1

// ---------------------------------------------------------------------------
// Phase 0: xqs = x / exp(w), xts = train_x / exp(w), plus row norms.
// ---------------------------------------------------------------------------
__global__ __launch_bounds__(256) void p0_scale(const float* __restrict__ x,
                                                const float* __restrict__ tx,
                                                const float* __restrict__ wts,
                                                float* __restrict__ xqs,
                                                float* __restrict__ xts,
                                                float* __restrict__ xqn,
                                                float* __restrict__ xtn) {
  int wid  = (blockIdx.x * blockDim.x + threadIdx.x) >> 6;
  int lane = threadIdx.x & 63;
  int row  = wid * 8 + (lane >> 3);
  int d0   = (lane & 7) * 4;
  if (row >= N_Q + M_T) return;
  const float* src; float* dst; float* ndst; int ri;
  if (row < N_Q) { src = x;  dst = xqs; ndst = xqn; ri = row; }
  else           { src = tx; dst = xts; ndst = xtn; ri = row - N_Q; }
  float4 v = *(const float4*)(src + (size_t)ri * D_ + d0);
  float s0 = expf(wts[d0 + 0]);
  float s1 = expf(wts[d0 + 1]);
  float s2 = expf(wts[d0 + 2]);
  float s3 = expf(wts[d0 + 3]);
  v.x /= s0; v.y /= s1; v.z /= s2; v.w /= s3;
  *(float4*)(dst + (size_t)ri * D_ + d0) = v;
  float nrm = v.x * v.x + v.y * v.y + v.z * v.z + v.w * v.w;
  nrm += __shfl_xor(nrm, 1);
  nrm += __shfl_xor(nrm, 2);
  nrm += __shfl_xor(nrm, 4);
  if ((lane & 7) == 0) ndst[ri] = nrm;
}

// ---------------------------------------------------------------------------
// Sorted-ascending top-5 insert, static register indices only.
// Caller guarantees v < s[4].
// ---------------------------------------------------------------------------
__device__ __forceinline__ void insert5(float (&s)[5], int (&id)[5], float v, int vi) {
  float cs = v; int ci = vi;
#pragma unroll
  for (int k = 0; k < 5; ++k) {
    bool lt   = cs < s[k];
    float ts  = s[k]; int ti = id[k];
    s[k]  = lt ? cs : ts;
    id[k] = lt ? ci : ti;
    cs    = lt ? ts : cs;
    ci    = lt ? ti : ci;
  }
}

// ---------------------------------------------------------------------------
// Phase 1: grid (NC chunks, 8 query-groups), 256 threads, 2 queries/thread.
// No min-wave bound: compiler free to keep the 64-float query tile register-
// resident (round 2's VGPR=116 < 128-needed proved rematerialization).
// Train tile staged in LDS, read wave-uniform (broadcast, conflict-free).
// psq chunk-major: each block writes one contiguous 10KB region.
// ---------------------------------------------------------------------------
__global__ __launch_bounds__(256) void p1_topk(const float* __restrict__ xqs,
                                               const float* __restrict__ xqn,
                                               const float* __restrict__ xts,
                                               const float* __restrict__ xtn,
                                               float* __restrict__ psq,
                                               int* __restrict__ pidx,
                                               int NC, int MB) {
  __shared__ float sxt[MBT * D_];
  __shared__ float sxtn[MBT];
  const int chunk = blockIdx.x;
  const int t     = threadIdx.x;
  const int q0    = blockIdx.y * (256 * QPT) + t * QPT;

  float xq[QPT][32];
  float qn[QPT];
#pragma unroll
  for (int q = 0; q < QPT; ++q) {
#pragma unroll
    for (int c = 0; c < 8; ++c) {
      float4 v = *(const float4*)(xqs + (size_t)(q0 + q) * D_ + c * 4);
      xq[q][c * 4 + 0] = v.x; xq[q][c * 4 + 1] = v.y;
      xq[q][c * 4 + 2] = v.z; xq[q][c * 4 + 3] = v.w;
    }
    qn[q] = xqn[q0 + q];
  }

  float s[QPT][5]; int id[QPT][5];
#pragma unroll
  for (int q = 0; q < QPT; ++q)
#pragma unroll
    for (int k = 0; k < 5; ++k) { s[q][k] = 3.0e38f; id[q][k] = 0; }

  const int jbase = chunk * MB;
  for (int tile = 0; tile < MB; tile += MBT) {
    __syncthreads();
#pragma unroll
    for (int c = 0; c < 4; ++c) {
      ((float4*)sxt)[t + c * 256] =
          ((const float4*)(xts + (size_t)(jbase + tile) * D_))[t + c * 256];
    }
    if (t < MBT) sxtn[t] = xtn[jbase + tile + t];
    __syncthreads();

    for (int j = 0; j < MBT; ++j) {
      const float* p = sxt + j * D_;
      float d0 = 0.f, d1 = 0.f;
#pragma unroll
      for (int c = 0; c < 8; ++c) {
        float4 v = *(const float4*)(p + c * 4);   // wave-uniform -> broadcast
        d0 = fmaf(xq[0][c * 4 + 0], v.x, d0);
        d0 = fmaf(xq[0][c * 4 + 1], v.y, d0);
        d0 = fmaf(xq[0][c * 4 + 2], v.z, d0);
        d0 = fmaf(xq[0][c * 4 + 3], v.w, d0);
        d1 = fmaf(xq[1][c * 4 + 0], v.x, d1);
        d1 = fmaf(xq[1][c * 4 + 1], v.y, d1);
        d1 = fmaf(xq[1][c * 4 + 2], v.z, d1);
        d1 = fmaf(xq[1][c * 4 + 3], v.w, d1);
      }
      const float tn = sxtn[j];
      const int   gj = jbase + tile + j;
      float sq0 = qn[0] + tn - 2.0f * d0;
      if (sq0 < s[0][4]) insert5(s[0], id[0], sq0, gj);
      float sq1 = qn[1] + tn - 2.0f * d1;
      if (sq1 < s[1][4]) insert5(s[1], id[1], sq1, gj);
    }
  }

#pragma unroll
  for (int q = 0; q < QPT; ++q)
#pragma unroll
    for (int k = 0; k < 5; ++k) {
      size_t base = ((size_t)chunk * N_Q + (q0 + q)) * 5 + k;
      psq [base] = s[q][k];
      pidx[base] = id[q][k];
    }
}

// ---------------------------------------------------------------------------
// Phase 2: one wave per query; lane-strided scan of NC*5 partials (chunk-major
// layout), shfl_xor butterfly merge, then weighted gather of train_y.
// ---------------------------------------------------------------------------
__global__ __launch_bounds__(256) void p2_merge(const float* __restrict__ psq,
                                               const int* __restrict__ pidx,
                                               const float* __restrict__ ty,
                                               float* __restrict__ out,
                                               int NC) {
  const int q    = (blockIdx.x * blockDim.x + threadIdx.x) >> 6;
  const int lane = threadIdx.x & 63;
  if (q >= N_Q) return;
  const int nc5 = NC * 5;

  float s[5]; int id[5];
#pragma unroll
  for (int k = 0; k < 5; ++k) { s[k] = 3.0e38f; id[k] = 0; }

  for (int c = lane; c < nc5; c += 64) {
    int chunk = c / 5;           // constant divisor -> magic multiply
    int k     = c - chunk * 5;
    size_t addr = ((size_t)chunk * N_Q + q) * 5 + k;
    float v = psq[addr];
    if (v < s[4]) insert5(s, id, v, pidx[addr]);
  }

#pragma unroll
  for (int step = 1; step < 64; step <<= 1) {
    float ov[5]; int oi[5];
#pragma unroll
    for (int k = 0; k < 5; ++k) {
      ov[k] = __shfl_xor(s[k], step);
      oi[k] = __shfl_xor(id[k], step);
    }
#pragma unroll
    for (int k = 0; k < 5; ++k) {
      if (ov[k] < s[4]) insert5(s, id, ov[k], oi[k]);
    }
  }

  float dinv[5]; float wsum = 0.f;
#pragma unroll
  for (int k = 0; k < 5; ++k) {
    dinv[k] = 1.0f / sqrtf(fmaxf(s[k], 0.f) + EPS_);
    wsum += dinv[k];
  }
  if (lane < OUT_) {
    float acc = 0.f;
#pragma unroll
    for (int k = 0; k < 5; ++k)
      acc = fmaf(dinv[k] / wsum, ty[(size_t)id[k] * OUT_ + lane], acc);
    out[(size_t)q * OUT_ + lane] = acc;
  }
}

// ---------------------------------------------------------------------------
extern "C" void kernel_launch(void* const* d_in, const int* in_sizes, int n_in,
                              void* d_out, int out_size, void* d_ws, size_t ws_size,
                              hipStream_t stream) {
  const float* x   = (const float*)d_in[0];
  const float* tx  = (const float*)d_in[1];
  const float* ty  = (const float*)d_in[2];
  const float* wts = (const float*)d_in[3];
  float* out = (float*)d_out;

  char* ws = (char*)d_ws;
  size_t off = 0;
  float* xqs = (float*)(ws + off); off += (size_t)N_Q * D_ * 4;
  float* xts = (float*)(ws + off); off += (size_t)M_T * D_ * 4;
  float* xqn = (float*)(ws + off); off += (size_t)N_Q * 4;
  float* xtn = (float*)(ws + off); off += (size_t)M_T * 4;

  int NC = 128;
  while (NC > 8) {
    size_t need = off + (size_t)N_Q * NC * 5 * 8;
    if (need <= ws_size) break;
    NC >>= 1;
  }
  const int MB = M_T / NC;
  float* psq  = (float*)(ws + off); off += (size_t)N_Q * NC * 5 * 4;
  int*   pidx = (int*)(ws + off);

  p0_scale<<<dim3((N_Q + M_T) / 32), dim3(256), 0, stream>>>(x, tx, wts, xqs, xts, xqn, xtn);
  p1_topk<<<dim3(NC, N_Q / (256 * QPT)), dim3(256), 0, stream>>>(xqs, xqn, xts, xtn, psq, pidx, NC, MB);
  p2_merge<<<dim3(N_Q * 64 / 256), dim3(256), 0, stream>>>(psq, pidx, ty, out, NC);
}

// Round 5
// 161.959 us; speedup vs baseline: 1.1609x; 1.1418x over previous
//
#include <hip/hip_runtime.h>

#define N_Q 4096
#define M_T 16384
#define D_ 32
#define OUT_ 16
#define EPS_ 1e-6f
#define NC_ 128              // M-chunks (one block column each)
#define MB_ (M_T / NC_)      // 128 points per chunk == one LDS tile
#define QPT 2                // queries per thread in phase 1
#define NKEY 8               // keys kept per (query, chunk)
#define NCAND 12             // candidates merged+rescored in phase 2

// ---------------------------------------------------------------------------
// Phase 0: xqs = x / exp(w), xts = train_x / exp(w), plus row norms.
// ---------------------------------------------------------------------------
__global__ __launch_bounds__(256) void p0_scale(const float* __restrict__ x,
                                                const float* __restrict__ tx,
                                                const float* __restrict__ wts,
                                                float* __restrict__ xqs,
                                                float* __restrict__ xts,
                                                float* __restrict__ xqn,
                                                float* __restrict__ xtn) {
  int wid  = (blockIdx.x * blockDim.x + threadIdx.x) >> 6;
  int lane = threadIdx.x & 63;
  int row  = wid * 8 + (lane >> 3);
  int d0   = (lane & 7) * 4;
  if (row >= N_Q + M_T) return;
  const float* src; float* dst; float* ndst; int ri;
  if (row < N_Q) { src = x;  dst = xqs; ndst = xqn; ri = row; }
  else           { src = tx; dst = xts; ndst = xtn; ri = row - N_Q; }
  float4 v = *(const float4*)(src + (size_t)ri * D_ + d0);
  float s0 = expf(wts[d0 + 0]);
  float s1 = expf(wts[d0 + 1]);
  float s2 = expf(wts[d0 + 2]);
  float s3 = expf(wts[d0 + 3]);
  v.x /= s0; v.y /= s1; v.z /= s2; v.w /= s3;
  *(float4*)(dst + (size_t)ri * D_ + d0) = v;
  float nrm = v.x * v.x + v.y * v.y + v.z * v.z + v.w * v.w;
  nrm += __shfl_xor(nrm, 1);
  nrm += __shfl_xor(nrm, 2);
  nrm += __shfl_xor(nrm, 4);
  if ((lane & 7) == 0) ndst[ri] = nrm;
}

// ---------------------------------------------------------------------------
// Exact (value,index) sorted-ascending top-5 insert, static indices only.
// ---------------------------------------------------------------------------
__device__ __forceinline__ void insert5(float (&s)[5], int (&id)[5], float v, int vi) {
  float cs = v; int ci = vi;
#pragma unroll
  for (int k = 0; k < 5; ++k) {
    bool lt   = cs < s[k];
    float ts  = s[k]; int ti = id[k];
    s[k]  = lt ? cs : ts;
    id[k] = lt ? ci : ti;
    cs    = lt ? ts : cs;
    ci    = lt ? ti : ci;
  }
}

// ---------------------------------------------------------------------------
// Phase 1: grid (NC_ chunks, 8 query-groups), 256 threads, QPT queries/thread.
// Branchless key selection: key = (bits(max(sq,0)) & 0xFFFFC000) | global_idx.
// sq >= 0 so fp32 bit pattern orders as u32; sorted top-8 maintained with a
// 16-op unconditional u32 min/max network (no divergence, no index cndmasks).
// pkey chunk-major: each block writes one contiguous 16KB region (coalesced).
// ---------------------------------------------------------------------------
__global__ __launch_bounds__(256, 1) void p1_topk(const float* __restrict__ xqs,
                                                  const float* __restrict__ xqn,
                                                  const float* __restrict__ xts,
                                                  const float* __restrict__ xtn,
                                                  unsigned int* __restrict__ pkey) {
  __shared__ float sxt[MB_ * D_];
  __shared__ float sxtn[MB_];
  const int chunk = blockIdx.x;
  const int t     = threadIdx.x;
  const int q0    = blockIdx.y * (256 * QPT) + t * QPT;

  {
    const float4* gsrc = (const float4*)(xts + (size_t)chunk * MB_ * D_);
#pragma unroll
    for (int c = 0; c < 4; ++c) ((float4*)sxt)[t + c * 256] = gsrc[t + c * 256];
    if (t < MB_) sxtn[t] = xtn[chunk * MB_ + t];
  }

  float xq[QPT][32]; float qn[QPT];
#pragma unroll
  for (int q = 0; q < QPT; ++q) {
#pragma unroll
    for (int c = 0; c < 8; ++c) {
      float4 v = *(const float4*)(xqs + (size_t)(q0 + q) * D_ + c * 4);
      xq[q][c * 4 + 0] = v.x; xq[q][c * 4 + 1] = v.y;
      xq[q][c * 4 + 2] = v.z; xq[q][c * 4 + 3] = v.w;
    }
    qn[q] = xqn[q0 + q];
  }

  unsigned int key[QPT][NKEY];
#pragma unroll
  for (int q = 0; q < QPT; ++q)
#pragma unroll
    for (int r = 0; r < NKEY; ++r) key[q][r] = 0xFFFFFFFFu;

  __syncthreads();

#pragma unroll 4
  for (int j = 0; j < MB_; ++j) {
    const float* p = sxt + j * D_;
    float d0 = 0.f, d1 = 0.f;
#pragma unroll
    for (int c = 0; c < 8; ++c) {
      float4 v = *(const float4*)(p + c * 4);   // wave-uniform -> LDS broadcast
      d0 = fmaf(xq[0][c * 4 + 0], v.x, d0);
      d0 = fmaf(xq[0][c * 4 + 1], v.y, d0);
      d0 = fmaf(xq[0][c * 4 + 2], v.z, d0);
      d0 = fmaf(xq[0][c * 4 + 3], v.w, d0);
      d1 = fmaf(xq[1][c * 4 + 0], v.x, d1);
      d1 = fmaf(xq[1][c * 4 + 1], v.y, d1);
      d1 = fmaf(xq[1][c * 4 + 2], v.z, d1);
      d1 = fmaf(xq[1][c * 4 + 3], v.w, d1);
    }
    const float tn = sxtn[j];
    const unsigned int gidx = (unsigned int)(chunk * MB_ + j);
    {
      float sq = fmaf(-2.0f, d0, qn[0] + tn);
      sq = fmaxf(sq, 0.0f);
      unsigned int k = (__float_as_uint(sq) & 0xFFFFC000u) | gidx;
#pragma unroll
      for (int r = 0; r < NKEY; ++r) {
        unsigned int lo = min(key[0][r], k);
        k = max(key[0][r], k);
        key[0][r] = lo;
      }
    }
    {
      float sq = fmaf(-2.0f, d1, qn[1] + tn);
      sq = fmaxf(sq, 0.0f);
      unsigned int k = (__float_as_uint(sq) & 0xFFFFC000u) | gidx;
#pragma unroll
      for (int r = 0; r < NKEY; ++r) {
        unsigned int lo = min(key[1][r], k);
        k = max(key[1][r], k);
        key[1][r] = lo;
      }
    }
  }

#pragma unroll
  for (int q = 0; q < QPT; ++q) {
    size_t base = ((size_t)chunk * N_Q + (q0 + q)) * NKEY;
    *(uint4*)(pkey + base)     = make_uint4(key[q][0], key[q][1], key[q][2], key[q][3]);
    *(uint4*)(pkey + base + 4) = make_uint4(key[q][4], key[q][5], key[q][6], key[q][7]);
  }
}

// ---------------------------------------------------------------------------
// Phase 2: one wave per query. Scan NC_*NKEY keys (16/lane), branchless merge
// to sorted top-12 via shfl_xor butterfly, exact fp32 rescore of the 12
// candidates, exact top-5, weights, gather train_y.
// ---------------------------------------------------------------------------
__global__ __launch_bounds__(256) void p2_merge(const unsigned int* __restrict__ pkey,
                                                const float* __restrict__ xqs,
                                                const float* __restrict__ xqn,
                                                const float* __restrict__ xts,
                                                const float* __restrict__ xtn,
                                                const float* __restrict__ ty,
                                                float* __restrict__ out) {
  const int q    = (blockIdx.x * blockDim.x + threadIdx.x) >> 6;
  const int lane = threadIdx.x & 63;
  if (q >= N_Q) return;

  unsigned int s[NCAND];
#pragma unroll
  for (int m = 0; m < NCAND; ++m) s[m] = 0xFFFFFFFFu;

#pragma unroll
  for (int i = 0; i < (NC_ * NKEY) / 64; ++i) {
    int c = lane + i * 64;
    unsigned int v = pkey[((size_t)(c >> 3) * N_Q + q) * NKEY + (c & 7)];
#pragma unroll
    for (int m = 0; m < NCAND; ++m) {
      unsigned int lo = min(s[m], v);
      v = max(s[m], v);
      s[m] = lo;
    }
  }

#pragma unroll
  for (int step = 1; step < 64; step <<= 1) {
    unsigned int ov[NCAND];
#pragma unroll
    for (int m = 0; m < NCAND; ++m) ov[m] = (unsigned int)__shfl_xor((int)s[m], step);
#pragma unroll
    for (int m = 0; m < NCAND; ++m) {
      unsigned int v = ov[m];
#pragma unroll
      for (int r = 0; r < NCAND; ++r) {
        unsigned int lo = min(s[r], v);
        v = max(s[r], v);
        s[r] = lo;
      }
    }
  }

  // lane m takes candidate m (static-index selection, no runtime reg indexing)
  unsigned int mykey = s[0];
#pragma unroll
  for (int m = 1; m < NCAND; ++m) mykey = (lane == m) ? s[m] : mykey;

  int   cidx = (int)(mykey & 0x3FFFu);
  float sqex = 3.0e38f;
  if (lane < NCAND) {
    float d = 0.f;
    const float* xr = xqs + (size_t)q * D_;
    const float* tr = xts + (size_t)cidx * D_;
#pragma unroll
    for (int c = 0; c < 8; ++c) {
      float4 a = *(const float4*)(xr + c * 4);
      float4 b = *(const float4*)(tr + c * 4);
      d = fmaf(a.x, b.x, d); d = fmaf(a.y, b.y, d);
      d = fmaf(a.z, b.z, d); d = fmaf(a.w, b.w, d);
    }
    sqex = fmaxf(xqn[q] + xtn[cidx] - 2.0f * d, 0.0f);
  }

  float s5[5]; int id5[5];
#pragma unroll
  for (int k = 0; k < 5; ++k) { s5[k] = 3.0e38f; id5[k] = 0; }
#pragma unroll
  for (int m = 0; m < NCAND; ++m) {
    float v  = __shfl(sqex, m);
    int   vi = __shfl(cidx, m);
    if (v < s5[4]) insert5(s5, id5, v, vi);   // wave-uniform branch
  }

  float dinv[5]; float wsum = 0.f;
#pragma unroll
  for (int k = 0; k < 5; ++k) {
    dinv[k] = 1.0f / sqrtf(s5[k] + EPS_);     // s5 already clamped >= 0
    wsum += dinv[k];
  }
  if (lane < OUT_) {
    float acc = 0.f;
#pragma unroll
    for (int k = 0; k < 5; ++k)
      acc = fmaf(dinv[k] / wsum, ty[(size_t)id5[k] * OUT_ + lane], acc);
    out[(size_t)q * OUT_ + lane] = acc;
  }
}

// ---------------------------------------------------------------------------
extern "C" void kernel_launch(void* const* d_in, const int* in_sizes, int n_in,
                              void* d_out, int out_size, void* d_ws, size_t ws_size,
                              hipStream_t stream) {
  const float* x   = (const float*)d_in[0];
  const float* tx  = (const float*)d_in[1];
  const float* ty  = (const float*)d_in[2];
  const float* wts = (const float*)d_in[3];
  float* out = (float*)d_out;

  char* ws = (char*)d_ws;
  size_t off = 0;
  float* xqs = (float*)(ws + off); off += (size_t)N_Q * D_ * 4;
  float* xts = (float*)(ws + off); off += (size_t)M_T * D_ * 4;
  float* xqn = (float*)(ws + off); off += (size_t)N_Q * 4;
  float* xtn = (float*)(ws + off); off += (size_t)M_T * 4;
  unsigned int* pkey = (unsigned int*)(ws + off);   // NC_*N_Q*NKEY*4 = 16.8MB

  p0_scale<<<dim3((N_Q + M_T) / 32), dim3(256), 0, stream>>>(x, tx, wts, xqs, xts, xqn, xtn);
  p1_topk<<<dim3(NC_, N_Q / (256 * QPT)), dim3(256), 0, stream>>>(xqs, xqn, xts, xtn, pkey);
  p2_merge<<<dim3(N_Q * 64 / 256), dim3(256), 0, stream>>>(pkey, xqs, xqn, xts, xtn, ty, out);
}